// Round 2
// baseline (279.463 us; speedup 1.0000x reference)
//
#include <hip/hip_runtime.h>
#include <math.h>

#define NB 4096
#define NS 50
#define NH 64
#define NITEM 40000
#define ROW4 (NITEM / 4)  // 10000 float4 per row

typedef float f4 __attribute__((ext_vector_type(4)));

// One block per batch row b. Phases:
//   1. 4 waves compute scores[b, s] (s interleaved across waves); lane i owns
//      output-dim i with Ur[i,:] held in 64 VGPRs; all_memory row addresses
//      are wave-uniform -> scalar/broadcast loads.
//   2. All 256 threads issue the 160 KB zero-fill of out[b, :] (after the
//      compute loads, so loads don't queue behind stores in the vmcnt FIFO).
//   3. __syncthreads (drains the stores), wave 0 does the 50-wide softmax.
//   4. Threads 0..49 atomicAdd probs onto the zeroed row (L2-resident lines,
//      same block -> no cross-block ordering needed). Duplicate items
//      accumulate exactly like the reference's .at[].add.
__global__ __launch_bounds__(256) void fused_row(
    const float* __restrict__ all_memory,   // [NB, NS, NH]
    const float* __restrict__ last_memory,  // [NB, NH]
    const float* __restrict__ Wr,           // [NH, NH]
    const float* __restrict__ Ur,           // [NH, NH]
    const float* __restrict__ Vr_w,         // [1, NH]
    const int* __restrict__ seq,            // [NB, NS]
    float* __restrict__ out)                // [NB, NITEM]
{
    __shared__ float sLDS[NS];   // raw scores
    __shared__ float pLDS[NS];   // softmax probs

    const int b = blockIdx.x;
    const int tid = (int)threadIdx.x;
    const int lane = tid & 63;
    const int warp = __builtin_amdgcn_readfirstlane(tid >> 6);

    // ---- phase 1: scores ----
    float ur[NH];
    {
        const float* urow = Ur + lane * NH;
        #pragma unroll
        for (int h = 0; h < NH; h += 4) {
            float4 u = *(const float4*)(urow + h);
            ur[h] = u.x; ur[h + 1] = u.y; ur[h + 2] = u.z; ur[h + 3] = u.w;
        }
    }
    float lm = 0.f;
    {
        const float* lrow = last_memory + b * NH;   // wave-uniform
        const float* wrow = Wr + lane * NH;
        #pragma unroll
        for (int h = 0; h < NH; h += 4) {
            float4 w = *(const float4*)(wrow + h);
            float4 l = *(const float4*)(lrow + h);
            lm += w.x * l.x + w.y * l.y + w.z * l.z + w.w * l.w;
        }
    }
    const float vw = Vr_w[lane];
    const float* am = all_memory + (long long)b * (NS * NH);

    for (int s = warp; s < NS; s += 4) {
        const float* arow = am + s * NH;            // wave-uniform
        float v0 = 0.f, v1 = 0.f, v2 = 0.f, v3 = 0.f;
        #pragma unroll
        for (int h = 0; h < NH; h += 4) {
            float4 a = *(const float4*)(arow + h);
            v0 += a.x * ur[h];
            v1 += a.y * ur[h + 1];
            v2 += a.z * ur[h + 2];
            v3 += a.w * ur[h + 3];
        }
        // Vr_b dropped: a constant shift of all scores cancels in softmax.
        float t = tanhf(lm + ((v0 + v1) + (v2 + v3))) * vw;
        #pragma unroll
        for (int off = 32; off >= 1; off >>= 1)
            t += __shfl_xor(t, off, 64);
        if (lane == 0) sLDS[s] = t;
    }

    // ---- phase 2: zero this row (issued after all compute loads) ----
    f4* orow4 = (f4*)(out + (long long)b * NITEM);
    const f4 z = (f4)(0.0f);
    for (int i = tid; i < ROW4; i += 256)
        orow4[i] = z;

    __syncthreads();   // drains zero stores + LDS score writes

    // ---- phase 3: softmax over 50 scores (wave 0) ----
    if (warp == 0) {
        float sc = (lane < NS) ? sLDS[lane] : -INFINITY;
        float m = sc;
        #pragma unroll
        for (int off = 32; off >= 1; off >>= 1)
            m = fmaxf(m, __shfl_xor(m, off, 64));
        float e = (lane < NS) ? expf(sc - m) : 0.f;
        float d = e;
        #pragma unroll
        for (int off = 32; off >= 1; off >>= 1)
            d += __shfl_xor(d, off, 64);
        if (lane < NS) pLDS[lane] = e / d;
    }
    __syncthreads();

    // ---- phase 4: scatter ----
    if (tid < NS) {
        int item = seq[b * NS + tid];
        atomicAdd(out + (long long)b * NITEM + item, pLDS[tid]);
    }
}

extern "C" void kernel_launch(void* const* d_in, const int* in_sizes, int n_in,
                              void* d_out, int out_size, void* d_ws, size_t ws_size,
                              hipStream_t stream) {
    const float* all_memory  = (const float*)d_in[0];
    const float* last_memory = (const float*)d_in[1];
    const float* Wr          = (const float*)d_in[2];
    const float* Ur          = (const float*)d_in[3];
    const float* Vr_w        = (const float*)d_in[4];
    // d_in[5] = Vr_b: constant shift of all scores, cancels in softmax.
    const int*   seq         = (const int*)d_in[6];
    float* out = (float*)d_out;

    fused_row<<<NB, 256, 0, stream>>>(all_memory, last_memory, Wr, Ur, Vr_w,
                                      seq, out);
}

// Round 3
// 240.621 us; speedup vs baseline: 1.1614x; 1.1614x over previous
//
#include <hip/hip_runtime.h>
#include <math.h>

#define NB 4096
#define NS 50
#define NH 64
#define NITEM 40000
#define ROW4 (NITEM / 4)  // 10000 float4 per row

typedef float f4 __attribute__((ext_vector_type(4)));

// One WAVE per batch row (64-thread blocks, no LDS, no __syncthreads):
//   1. lane i owns output-dim i; Ur[i,:] lives in 64 VGPRs. Row addresses of
//      all_memory are wave-uniform -> scalar/broadcast loads. Wave computes
//      all 50 scores; lane s keeps score[b,s].
//   2. Wave zeroes its own 160 KB output row with plain float4 stores
//      (plain, NOT nontemporal: lines stay in L2 so step 4's atomics hit L2).
//   3. Softmax over lanes 0..49 via shfl — pure VALU, overlaps store drain.
//   4. s_waitcnt vmcnt(0), then lanes 0..49 atomicAdd probs onto the
//      freshly-zeroed row (same wave -> ordering is just the waitcnt;
//      duplicates accumulate exactly like the reference's .at[].add).
// 16 independent 1-wave blocks per CU retire/refill individually -> stores
// from some waves always overlap compute of others (no grid-wide convoy).
__global__ __launch_bounds__(64) void fused_row(
    const float* __restrict__ all_memory,   // [NB, NS, NH]
    const float* __restrict__ last_memory,  // [NB, NH]
    const float* __restrict__ Wr,           // [NH, NH]
    const float* __restrict__ Ur,           // [NH, NH]
    const float* __restrict__ Vr_w,         // [1, NH]
    const int* __restrict__ seq,            // [NB, NS]
    float* __restrict__ out)                // [NB, NITEM]
{
    const int b = blockIdx.x;
    const int lane = (int)threadIdx.x;      // 0..63

    // Hoist the scatter index load (coalesced, tiny).
    int item = (lane < NS) ? seq[b * NS + lane] : 0;

    // ---- phase 1: scores ----
    float ur[NH];
    {
        const float* urow = Ur + lane * NH;
        #pragma unroll
        for (int h = 0; h < NH; h += 4) {
            float4 u = *(const float4*)(urow + h);
            ur[h] = u.x; ur[h + 1] = u.y; ur[h + 2] = u.z; ur[h + 3] = u.w;
        }
    }
    float lm = 0.f;
    {
        const float* lrow = last_memory + b * NH;   // wave-uniform
        const float* wrow = Wr + lane * NH;
        #pragma unroll
        for (int h = 0; h < NH; h += 4) {
            float4 w = *(const float4*)(wrow + h);
            float4 l = *(const float4*)(lrow + h);
            lm += w.x * l.x + w.y * l.y + w.z * l.z + w.w * l.w;
        }
    }
    const float vw = Vr_w[lane];
    const float* am = all_memory + (long long)b * (NS * NH);

    float myscore = 0.f;
    for (int s = 0; s < NS; ++s) {
        const float* arow = am + s * NH;            // wave-uniform
        float v0 = 0.f, v1 = 0.f, v2 = 0.f, v3 = 0.f;
        #pragma unroll
        for (int h = 0; h < NH; h += 4) {
            float4 a = *(const float4*)(arow + h);
            v0 += a.x * ur[h];
            v1 += a.y * ur[h + 1];
            v2 += a.z * ur[h + 2];
            v3 += a.w * ur[h + 3];
        }
        // Vr_b dropped: constant score shift cancels in softmax.
        float t = tanhf(lm + ((v0 + v1) + (v2 + v3))) * vw;
        #pragma unroll
        for (int off = 32; off >= 1; off >>= 1)
            t += __shfl_xor(t, off, 64);
        myscore = (lane == s) ? t : myscore;
    }

    // ---- phase 2: zero this row (plain stores -> L2-resident) ----
    f4* orow4 = (f4*)(out + (long long)b * NITEM);
    const f4 z = (f4)(0.0f);
    for (int i = lane; i < ROW4; i += 64)
        orow4[i] = z;

    // ---- phase 3: in-wave softmax (hides under store drain) ----
    float sc = (lane < NS) ? myscore : -INFINITY;
    float m = sc;
    #pragma unroll
    for (int off = 32; off >= 1; off >>= 1)
        m = fmaxf(m, __shfl_xor(m, off, 64));
    float e = (lane < NS) ? expf(sc - m) : 0.f;
    float d = e;
    #pragma unroll
    for (int off = 32; off >= 1; off >>= 1)
        d += __shfl_xor(d, off, 64);
    float p = e / d;

    // ---- phase 4: drain stores, then scatter onto own row ----
    asm volatile("s_waitcnt vmcnt(0)" ::: "memory");
    if (lane < NS)
        atomicAdd(out + (long long)b * NITEM + item, p);
}

extern "C" void kernel_launch(void* const* d_in, const int* in_sizes, int n_in,
                              void* d_out, int out_size, void* d_ws, size_t ws_size,
                              hipStream_t stream) {
    const float* all_memory  = (const float*)d_in[0];
    const float* last_memory = (const float*)d_in[1];
    const float* Wr          = (const float*)d_in[2];
    const float* Ur          = (const float*)d_in[3];
    const float* Vr_w        = (const float*)d_in[4];
    // d_in[5] = Vr_b: constant shift of all scores, cancels in softmax.
    const int*   seq         = (const int*)d_in[6];
    float* out = (float*)d_out;

    fused_row<<<NB, 64, 0, stream>>>(all_memory, last_memory, Wr, Ur, Vr_w,
                                     seq, out);
}